// Round 3
// baseline (1526.760 us; speedup 1.0000x reference)
//
#include <hip/hip_runtime.h>
#include <hip/hip_bf16.h>

#define NN 50000
#define EE 800000
#define DD 100
#define HH 16
#define CC 40
#define NCELL 12

// ---------------- graph preprocessing ----------------

__global__ __launch_bounds__(256) void k_hist(const int* __restrict__ er, int* __restrict__ cnt) {
    int e = blockIdx.x * 256 + threadIdx.x;
    if (e < EE) atomicAdd(&cnt[er[e]], 1);
}

__global__ __launch_bounds__(256) void k_dinv(const int* __restrict__ cnt, float* __restrict__ dinv) {
    int i = blockIdx.x * 256 + threadIdx.x;
    if (i < NN) dinv[i] = rsqrtf((float)(cnt[i] + 1));   // +1 self loop
}

// single-block exclusive scan of cnt -> rp, cursor
__global__ __launch_bounds__(1024) void k_scan(const int* __restrict__ cnt, int* __restrict__ rp,
                                               int* __restrict__ cursor) {
    __shared__ int lds[1024];
    __shared__ int carry_s;
    int t = threadIdx.x;
    if (t == 0) carry_s = 0;
    __syncthreads();
    for (int base = 0; base < NN; base += 1024) {
        int i = base + t;
        int v = (i < NN) ? cnt[i] : 0;
        lds[t] = v;
        __syncthreads();
        #pragma unroll
        for (int off = 1; off < 1024; off <<= 1) {
            int x = lds[t];
            int y = (t >= off) ? lds[t - off] : 0;
            __syncthreads();
            lds[t] = x + y;
            __syncthreads();
        }
        int incl = lds[t];
        int carry = carry_s;
        int excl = carry + incl - v;
        if (i < NN) { rp[i] = excl; cursor[i] = excl; }
        __syncthreads();
        if (t == 1023) carry_s = carry + lds[1023];
        __syncthreads();
    }
    if (t == 0) rp[NN] = carry_s;
}

__global__ __launch_bounds__(256) void k_fill(const int* __restrict__ er, const int* __restrict__ ec,
                                              const float* __restrict__ dinv, int* __restrict__ cursor,
                                              int* __restrict__ ci, float* __restrict__ cv) {
    int e = blockIdx.x * 256 + threadIdx.x;
    if (e >= EE) return;
    int r = er[e], c = ec[e];
    int p = atomicAdd(&cursor[r], 1);
    ci[p] = c;
    cv[p] = dinv[r] * dinv[c];
}

// ---------------- row L2 normalize: xn = x / max(||x||,1e-12) ----------------
__global__ __launch_bounds__(256) void k_norm(const float* __restrict__ x, float* __restrict__ xn) {
    int wid = (blockIdx.x * 256 + threadIdx.x) >> 6;
    int lane = threadIdx.x & 63;
    if (wid >= NN) return;
    const size_t base = (size_t)wid * DD;
    float a = x[base + lane];
    float b = (lane < DD - 64) ? x[base + 64 + lane] : 0.f;
    float ss = a * a + b * b;
    #pragma unroll
    for (int off = 1; off < 64; off <<= 1) ss += __shfl_xor(ss, off);
    float inv = 1.f / fmaxf(sqrtf(ss), 1e-12f);
    xn[base + lane] = a * inv;
    if (lane < DD - 64) xn[base + 64 + lane] = b * inv;
}

// ---------------- SpMM: out = (D^-1/2 (A+I) D^-1/2) @ in, CSR gather, wave per row ----------------
template <int F>
__global__ __launch_bounds__(256) void k_spmm(const int* __restrict__ rp, const int* __restrict__ ci,
                                              const float* __restrict__ cv, const float* __restrict__ dinv,
                                              const float* __restrict__ in, float* __restrict__ out) {
    constexpr int J = (F + 63) / 64;
    int wid = (blockIdx.x * 256 + threadIdx.x) >> 6;
    int lane = threadIdx.x & 63;
    if (wid >= NN) return;
    float d = dinv[wid];
    float sw = d * d;
    float acc[J];
    #pragma unroll
    for (int j = 0; j < J; j++) {
        int f = lane + 64 * j;
        acc[j] = (f < F) ? sw * in[(size_t)wid * F + f] : 0.f;
    }
    int s = rp[wid], e = rp[wid + 1];
    for (int p = s; p < e; p++) {
        int c = ci[p];
        float v = cv[p];
        #pragma unroll
        for (int j = 0; j < J; j++) {
            int f = lane + 64 * j;
            if (f < F) acc[j] += v * in[(size_t)c * F + f];
        }
    }
    #pragma unroll
    for (int j = 0; j < J; j++) {
        int f = lane + 64 * j;
        if (f < F) out[(size_t)wid * F + f] = acc[j];
    }
}

// ---------------- hidden: hid[N,48] = relu(BN(xs @ W1cat_h + b1cat_h)) ----------------
// 8 nodes per block, 384 threads = 8 nodes x 48 cols
__global__ __launch_bounds__(384) void k_hid(const float* __restrict__ xs, const float* __restrict__ W1,
                                             const float* __restrict__ b1, const float* __restrict__ gamma,
                                             const float* __restrict__ beta, const float* __restrict__ bn_mean,
                                             const float* __restrict__ bn_var, float* __restrict__ hid, int h) {
    __shared__ float wl[DD][48];
    __shared__ float xl[8][DD];
    __shared__ float scale_l[48], shift_l[48];
    int t = threadIdx.x;
    for (int idx = t; idx < DD * 48; idx += 384) {
        int k = idx / 48, cc = idx % 48;
        int r = cc / 16, j = cc % 16;
        wl[k][cc] = W1[(size_t)(r * 4 + h) * (DD * HH) + k * HH + j];
    }
    if (t < 48) {
        int r = t / 16, j = t % 16;
        int i = r * 4 + h;
        float g  = gamma[i * HH + j];
        float be = beta[i * HH + j];
        float m  = bn_mean[i * HH + j];
        float v  = bn_var[i * HH + j];
        float bb = b1[i * HH + j];
        float sc = g * rsqrtf(v + 1e-5f);
        scale_l[t] = sc;
        shift_l[t] = (bb - m) * sc + be;
    }
    int node0 = blockIdx.x * 8;
    for (int idx = t; idx < 8 * DD; idx += 384) {
        int nl = idx / DD, k = idx % DD;
        int n = node0 + nl;
        xl[nl][k] = (n < NN) ? xs[(size_t)n * DD + k] : 0.f;
    }
    __syncthreads();
    int nl = t / 48, cc = t % 48;
    int n = node0 + nl;
    if (n < NN) {
        float s = 0.f;
        #pragma unroll
        for (int k = 0; k < DD; k++) s += xl[nl][k] * wl[k][cc];
        float hv = s * scale_l[cc] + shift_l[cc];
        hid[(size_t)n * 48 + cc] = fmaxf(hv, 0.f);
    }
}

// ---------------- cell outputs: for r=0..2, cell i=r*4+h: out_i = hid[:,r*16:+16] @ W2[i] + b2[i] ----------------
// 2 nodes per block, 240 of 256 threads used (2 x 3r x 40c)
__global__ __launch_bounds__(256) void k_cellout(const float* __restrict__ hid, const float* __restrict__ W2,
                                                 const float* __restrict__ b2v, float* __restrict__ outcell, int h) {
    __shared__ float w2l[3][16][40];
    __shared__ float b2l[3][40];
    __shared__ float hl[2][48];
    int t = threadIdx.x;
    for (int idx = t; idx < 3 * 16 * 40; idx += 256) {
        int r = idx / 640, rem = idx % 640, k = rem / 40, c = rem % 40;
        w2l[r][k][c] = W2[(size_t)(r * 4 + h) * (HH * CC) + k * CC + c];
    }
    if (t < 120) {
        int r = t / 40, c = t % 40;
        b2l[r][c] = b2v[(r * 4 + h) * CC + c];
    }
    int node0 = blockIdx.x * 2;
    for (int idx = t; idx < 2 * 48; idx += 256) {
        int nl = idx / 48, k = idx % 48;
        int n = node0 + nl;
        hl[nl][k] = (n < NN) ? hid[(size_t)n * 48 + k] : 0.f;
    }
    __syncthreads();
    if (t < 240) {
        int nl = t / 120, rc = t % 120, r = rc / 40, c = rc % 40;
        int n = node0 + nl;
        if (n < NN) {
            float s = b2l[r][c];
            #pragma unroll
            for (int k = 0; k < 16; k++) s += hl[nl][r * 16 + k] * w2l[r][k][c];
            int i = r * 4 + h;
            outcell[(size_t)n * (NCELL * CC) + i * CC + c] = s;
        }
    }
}

// ---------------- final: output = relu(cell[N,480]) @ Wout + bout ----------------
// 6 nodes per block, 240 of 256 threads used
__global__ __launch_bounds__(256) void k_final(const float* __restrict__ cell, const float* __restrict__ Wout,
                                               const float* __restrict__ bout, float* __restrict__ out) {
    __shared__ float cl[6][NCELL * CC];
    int t = threadIdx.x;
    int node0 = blockIdx.x * 6;
    for (int idx = t; idx < 6 * NCELL * CC; idx += 256) {
        int nl = idx / (NCELL * CC), k = idx % (NCELL * CC);
        int n = node0 + nl;
        cl[nl][k] = (n < NN) ? fmaxf(cell[(size_t)n * (NCELL * CC) + k], 0.f) : 0.f;
    }
    __syncthreads();
    if (t < 240) {
        int nl = t / 40, c = t % 40;
        int n = node0 + nl;
        if (n < NN) {
            float s = bout[c];
            for (int k = 0; k < NCELL * CC; k++) s += cl[nl][k] * Wout[k * CC + c];
            out[(size_t)n * CC + c] = s;
        }
    }
}

// ---------------- host ----------------

extern "C" void kernel_launch(void* const* d_in, const int* in_sizes, int n_in,
                              void* d_out, int out_size, void* d_ws, size_t ws_size,
                              hipStream_t stream) {
    const float* x       = (const float*)d_in[0];
    const int*   er      = (const int*)d_in[1];
    const int*   ec      = (const int*)d_in[2];
    const float* W1      = (const float*)d_in[3];
    const float* b1      = (const float*)d_in[4];
    const float* gamma   = (const float*)d_in[5];
    const float* beta    = (const float*)d_in[6];
    const float* bn_mean = (const float*)d_in[7];
    const float* bn_var  = (const float*)d_in[8];
    const float* W2      = (const float*)d_in[9];
    const float* b2v     = (const float*)d_in[10];
    const float* Wout    = (const float*)d_in[11];
    const float* bout    = (const float*)d_in[12];

    float* out     = (float*)d_out;               // [N, C] f32
    float* outcell = out + (size_t)NN * CC;       // [N, NC, C] f32

    // workspace carve-out (f32/int32), 256B aligned
    char* w = (char*)d_ws;
    auto alloc = [&](size_t bytes) {
        void* p = (void*)w;
        w += (bytes + 255) & ~(size_t)255;
        return p;
    };
    int*   cnt    = (int*)alloc((size_t)NN * 4);
    int*   rp     = (int*)alloc((size_t)(NN + 1) * 4);
    int*   cursor = (int*)alloc((size_t)NN * 4);
    float* dinv   = (float*)alloc((size_t)NN * 4);
    int*   ci     = (int*)alloc((size_t)EE * 4);
    float* cv     = (float*)alloc((size_t)EE * 4);
    float* xsA    = (float*)alloc((size_t)NN * DD * 4);
    float* xsB    = (float*)alloc((size_t)NN * DD * 4);
    float* hidA   = (float*)alloc((size_t)NN * 48 * 4);
    float* hidB   = (float*)alloc((size_t)NN * 48 * 4);

    hipMemsetAsync(cnt, 0, (size_t)NN * 4, stream);

    int gE = (EE + 255) / 256;
    int gN = (NN + 255) / 256;
    k_hist<<<gE, 256, 0, stream>>>(er, cnt);
    k_dinv<<<gN, 256, 0, stream>>>(cnt, dinv);
    k_scan<<<1, 1024, 0, stream>>>(cnt, rp, cursor);
    k_fill<<<gE, 256, 0, stream>>>(er, ec, dinv, cursor, ci, cv);

    int gW = (NN + 3) / 4;  // wave per node, 4 waves/block
    k_norm<<<gW, 256, 0, stream>>>(x, xsA);

    float* xs_cur = xsA;
    float* xs_nxt = xsB;
    for (int h = 0; h <= 3; h++) {
        k_hid<<<(NN + 7) / 8, 384, 0, stream>>>(xs_cur, W1, b1, gamma, beta, bn_mean, bn_var, hidA, h);
        float* hc = hidA;
        float* hn = hidB;
        for (int s = 0; s < h; s++) {
            k_spmm<48><<<gW, 256, 0, stream>>>(rp, ci, cv, dinv, hc, hn);
            float* tmp = hc; hc = hn; hn = tmp;
        }
        k_cellout<<<(NN + 1) / 2, 256, 0, stream>>>(hc, W2, b2v, outcell, h);
        if (h < 3) {
            k_spmm<DD><<<gW, 256, 0, stream>>>(rp, ci, cv, dinv, xs_cur, xs_nxt);
            float* tmp = xs_cur; xs_cur = xs_nxt; xs_nxt = tmp;
        }
    }
    k_final<<<(NN + 5) / 6, 256, 0, stream>>>(outcell, Wout, bout, out);
}

// Round 4
// 1132.554 us; speedup vs baseline: 1.3481x; 1.3481x over previous
//
#include <hip/hip_runtime.h>
#include <hip/hip_bf16.h>

#define NN 50000
#define EE 800000
#define DD 100
#define HH 16
#define CC 40
#define NCELL 12
#define NB_SCAN 49   // ceil(50000/1024)

// ---------------- graph preprocessing ----------------

__global__ __launch_bounds__(256) void k_hist(const int* __restrict__ er, int* __restrict__ cnt) {
    int e = blockIdx.x * 256 + threadIdx.x;
    if (e < EE) atomicAdd(&cnt[er[e]], 1);
}

__global__ __launch_bounds__(256) void k_dinv(const int* __restrict__ cnt, float* __restrict__ dinv) {
    int i = blockIdx.x * 256 + threadIdx.x;
    if (i < NN) dinv[i] = rsqrtf((float)(cnt[i] + 1));   // +1 self loop
}

// two-level scan: per-block exclusive scan + block totals
__global__ __launch_bounds__(1024) void k_scan1(const int* __restrict__ cnt, int* __restrict__ rp,
                                                int* __restrict__ bsum) {
    __shared__ int lds[1024];
    int t = threadIdx.x, i = blockIdx.x * 1024 + t;
    int v = (i < NN) ? cnt[i] : 0;
    lds[t] = v;
    __syncthreads();
    #pragma unroll
    for (int off = 1; off < 1024; off <<= 1) {
        int x = lds[t];
        int y = (t >= off) ? lds[t - off] : 0;
        __syncthreads();
        lds[t] = x + y;
        __syncthreads();
    }
    if (i < NN) rp[i] = lds[t] - v;           // local exclusive
    if (t == 1023) bsum[blockIdx.x] = lds[1023];
}

__global__ __launch_bounds__(64) void k_scan2(int* __restrict__ bsum) {
    int t = threadIdx.x;
    int orig = (t < NB_SCAN) ? bsum[t] : 0;
    int v = orig;
    #pragma unroll
    for (int off = 1; off < 64; off <<= 1) {
        int y = __shfl_up(v, off);
        if (t >= off) v += y;
    }
    if (t < NB_SCAN) bsum[t] = v - orig;      // exclusive
    if (t == NB_SCAN - 1) bsum[NB_SCAN] = v;  // total
}

__global__ __launch_bounds__(256) void k_scan3(int* __restrict__ rp, int* __restrict__ cursor,
                                               const int* __restrict__ bsum) {
    int i = blockIdx.x * 256 + threadIdx.x;
    if (i < NN) {
        int v = rp[i] + bsum[i >> 10];
        rp[i] = v;
        cursor[i] = v;
    }
    if (i == 0) rp[NN] = bsum[NB_SCAN];
}

__global__ __launch_bounds__(256) void k_fill(const int* __restrict__ er, const int* __restrict__ ec,
                                              const float* __restrict__ dinv, int* __restrict__ cursor,
                                              int* __restrict__ ci, float* __restrict__ cv) {
    int e = blockIdx.x * 256 + threadIdx.x;
    if (e >= EE) return;
    int r = er[e], c = ec[e];
    int p = atomicAdd(&cursor[r], 1);
    ci[p] = c;
    cv[p] = dinv[r] * dinv[c];
}

// ---------------- row L2 normalize ----------------
__global__ __launch_bounds__(256) void k_norm(const float* __restrict__ x, float* __restrict__ xn) {
    int wid = (blockIdx.x * 256 + threadIdx.x) >> 6;
    int lane = threadIdx.x & 63;
    if (wid >= NN) return;
    const size_t base = (size_t)wid * DD;
    float a = x[base + lane];
    float b = (lane < DD - 64) ? x[base + 64 + lane] : 0.f;
    float ss = a * a + b * b;
    #pragma unroll
    for (int off = 1; off < 64; off <<= 1) ss += __shfl_xor(ss, off);
    float inv = 1.f / fmaxf(sqrtf(ss), 1e-12f);
    xn[base + lane] = a * inv;
    if (lane < DD - 64) xn[base + 64 + lane] = b * inv;
}

// ---------------- SpMM with strides/offsets, wave per row, ci/cv prefetch ----------------
template <int F>
__global__ __launch_bounds__(256) void k_spmm(const int* __restrict__ rp, const int* __restrict__ ci,
                                              const float* __restrict__ cv, const float* __restrict__ dinv,
                                              const float* __restrict__ in, int ins, int ioff,
                                              float* __restrict__ out, int outs) {
    constexpr int J = (F + 63) / 64;
    int wid = (blockIdx.x * 256 + threadIdx.x) >> 6;
    int lane = threadIdx.x & 63;
    if (wid >= NN) return;
    const float* ib = in + ioff;
    float d = dinv[wid];
    float sw = d * d;
    float acc[J];
    #pragma unroll
    for (int j = 0; j < J; j++) {
        int f = lane + 64 * j;
        acc[j] = (f < F) ? sw * ib[(size_t)wid * ins + f] : 0.f;
    }
    int s = rp[wid], e = rp[wid + 1];
    int p = s;
    int cA = 0; float vA = 0.f;
    if (p < e) { cA = ci[p]; vA = cv[p]; }
    while (p < e) {
        int pn = p + 1;
        int cB = 0; float vB = 0.f;
        if (pn < e) { cB = ci[pn]; vB = cv[pn]; }     // prefetch next edge
        size_t b = (size_t)cA * ins;
        #pragma unroll
        for (int j = 0; j < J; j++) {
            int f = lane + 64 * j;
            if (f < F) acc[j] += vA * ib[b + f];
        }
        cA = cB; vA = vB; p = pn;
    }
    #pragma unroll
    for (int j = 0; j < J; j++) {
        int f = lane + 64 * j;
        if (f < F) out[(size_t)wid * outs + f] = acc[j];
    }
}

// ---------------- hidden: thread-per-node, uniform-scalar weights ----------------
// hid[n*hs + hoff + cc] = relu(BN(xs[n] @ W1cat_h + b1cat_h)), cc in [0,48)
__global__ __launch_bounds__(256) void k_hid(const float* __restrict__ xs, const float* __restrict__ W1,
                                             const float* __restrict__ b1, const float* __restrict__ gamma,
                                             const float* __restrict__ beta, const float* __restrict__ bn_mean,
                                             const float* __restrict__ bn_var, float* __restrict__ hid,
                                             int hs, int hoff, int h) {
    int n = blockIdx.x * 256 + threadIdx.x;
    if (n >= NN) return;
    float acc[48];
    #pragma unroll
    for (int cc = 0; cc < 48; cc++) acc[cc] = 0.f;
    const float4* xr = (const float4*)(xs + (size_t)n * DD);
    for (int kq = 0; kq < DD / 4; kq++) {
        float4 xv4 = xr[kq];
        float xv[4] = {xv4.x, xv4.y, xv4.z, xv4.w};
        #pragma unroll
        for (int u = 0; u < 4; u++) {
            int k = kq * 4 + u;
            #pragma unroll
            for (int cc = 0; cc < 48; cc++) {
                int r = cc / 16, j = cc % 16;
                acc[cc] += xv[u] * W1[((size_t)(r * 4 + h) * DD + k) * HH + j];  // uniform -> s_load
            }
        }
    }
    float* hr = hid + (size_t)n * hs + hoff;
    #pragma unroll
    for (int cc = 0; cc < 48; cc++) {
        int r = cc / 16, j = cc % 16;
        int i = (r * 4 + h) * HH + j;
        float sc = gamma[i] * rsqrtf(bn_var[i] + 1e-5f);
        float sh = (b1[i] - bn_mean[i]) * sc + beta[i];
        hr[cc] = fmaxf(acc[cc] * sc + sh, 0.f);
    }
}

// ---------------- cell outputs: thread-per-(node,replica), uniform-scalar W2 ----------------
__global__ __launch_bounds__(256) void k_cellout(const float* __restrict__ hid, int hs, int hoff,
                                                 const float* __restrict__ W2, const float* __restrict__ b2v,
                                                 float* __restrict__ outcell, int h) {
    int n = blockIdx.x * 256 + threadIdx.x;
    int r = blockIdx.y;
    if (n >= NN) return;
    const float* hr = hid + (size_t)n * hs + hoff + r * HH;
    float x[HH];
    #pragma unroll
    for (int q = 0; q < HH / 4; q++) {
        float4 v = *(const float4*)(hr + 4 * q);
        x[4 * q + 0] = v.x; x[4 * q + 1] = v.y; x[4 * q + 2] = v.z; x[4 * q + 3] = v.w;
    }
    int cell = r * 4 + h;
    const float* wv = W2 + (size_t)cell * (HH * CC);
    float acc[CC];
    #pragma unroll
    for (int c = 0; c < CC; c++) acc[c] = b2v[cell * CC + c];   // uniform
    #pragma unroll
    for (int k = 0; k < HH; k++) {
        #pragma unroll
        for (int c = 0; c < CC; c++) acc[c] += x[k] * wv[k * CC + c];  // uniform -> s_load
    }
    float* o = outcell + (size_t)n * (NCELL * CC) + cell * CC;
    #pragma unroll
    for (int q = 0; q < CC / 4; q++)
        *(float4*)(o + 4 * q) = make_float4(acc[4 * q], acc[4 * q + 1], acc[4 * q + 2], acc[4 * q + 3]);
}

// ---------------- final: thread-per-node, uniform-scalar Wout ----------------
__global__ __launch_bounds__(256) void k_final(const float* __restrict__ cell, const float* __restrict__ Wout,
                                               const float* __restrict__ bout, float* __restrict__ out) {
    int n = blockIdx.x * 256 + threadIdx.x;
    if (n >= NN) return;
    float acc[CC];
    #pragma unroll
    for (int c = 0; c < CC; c++) acc[c] = bout[c];              // uniform
    const float4* row = (const float4*)(cell + (size_t)n * (NCELL * CC));
    for (int kq = 0; kq < (NCELL * CC) / 4; kq++) {
        float4 v = row[kq];
        float xv[4] = {fmaxf(v.x, 0.f), fmaxf(v.y, 0.f), fmaxf(v.z, 0.f), fmaxf(v.w, 0.f)};
        #pragma unroll
        for (int u = 0; u < 4; u++) {
            int k = kq * 4 + u;
            #pragma unroll
            for (int c = 0; c < CC; c++) acc[c] += xv[u] * Wout[(size_t)k * CC + c];  // uniform -> s_load
        }
    }
    float* o = out + (size_t)n * CC;
    #pragma unroll
    for (int q = 0; q < CC / 4; q++)
        *(float4*)(o + 4 * q) = make_float4(acc[4 * q], acc[4 * q + 1], acc[4 * q + 2], acc[4 * q + 3]);
}

// ---------------- host ----------------

extern "C" void kernel_launch(void* const* d_in, const int* in_sizes, int n_in,
                              void* d_out, int out_size, void* d_ws, size_t ws_size,
                              hipStream_t stream) {
    const float* x       = (const float*)d_in[0];
    const int*   er      = (const int*)d_in[1];
    const int*   ec      = (const int*)d_in[2];
    const float* W1      = (const float*)d_in[3];
    const float* b1      = (const float*)d_in[4];
    const float* gamma   = (const float*)d_in[5];
    const float* beta    = (const float*)d_in[6];
    const float* bn_mean = (const float*)d_in[7];
    const float* bn_var  = (const float*)d_in[8];
    const float* W2      = (const float*)d_in[9];
    const float* b2v     = (const float*)d_in[10];
    const float* Wout    = (const float*)d_in[11];
    const float* bout    = (const float*)d_in[12];

    float* out     = (float*)d_out;               // [N, C] f32
    float* outcell = out + (size_t)NN * CC;       // [N, NC, C] f32

    char* w = (char*)d_ws;
    auto alloc = [&](size_t bytes) {
        void* p = (void*)w;
        w += (bytes + 255) & ~(size_t)255;
        return p;
    };
    int*   cnt    = (int*)alloc((size_t)NN * 4);
    int*   rp     = (int*)alloc((size_t)(NN + 1) * 4);
    int*   cursor = (int*)alloc((size_t)NN * 4);
    float* dinv   = (float*)alloc((size_t)NN * 4);
    int*   bsum   = (int*)alloc((size_t)(NB_SCAN + 1) * 4);
    int*   ci     = (int*)alloc((size_t)EE * 4);
    float* cv     = (float*)alloc((size_t)EE * 4);
    float* xsA    = (float*)alloc((size_t)NN * DD * 4);   // xs arena part 1 (20MB)
    float* xsB    = (float*)alloc((size_t)NN * DD * 4);   // xs arena part 2 (20MB)
    float* hid3   = (float*)alloc((size_t)NN * 144 * 4);  // [N,144]: h=1|2|3 cols (28.8MB)
    // overlays (regions proven dead at time of reuse):
    float* S1 = xsA;    // [N,144] after xs arena is dead (28.8 <= 40MB)
    float* S2 = hid3;   // [N,96]  after hid3 is dead
    float* S3 = xsA;    // [N,48]  after S1 is dead

    hipMemsetAsync(cnt, 0, (size_t)NN * 4, stream);

    int gE = (EE + 255) / 256;
    int gN = (NN + 255) / 256;
    int gW = (NN + 3) / 4;   // spmm: wave per row

    k_hist<<<gE, 256, 0, stream>>>(er, cnt);
    k_dinv<<<gN, 256, 0, stream>>>(cnt, dinv);
    k_scan1<<<NB_SCAN, 1024, 0, stream>>>(cnt, rp, bsum);
    k_scan2<<<1, 64, 0, stream>>>(bsum);
    k_scan3<<<gN, 256, 0, stream>>>(rp, cursor, bsum);
    k_fill<<<gE, 256, 0, stream>>>(er, ec, dinv, cursor, ci, cv);

    k_norm<<<gW, 256, 0, stream>>>(x, xsA);

    // h=0: hid -> hid3 cols 0:48 (temporary), cellout h=0 consumes before h=1 overwrites
    k_hid<<<gN, 256, 0, stream>>>(xsA, W1, b1, gamma, beta, bn_mean, bn_var, hid3, 144, 0, 0);
    k_cellout<<<dim3(gN, 3), 256, 0, stream>>>(hid3, 144, 0, W2, b2v, outcell, 0);

    k_spmm<DD><<<gW, 256, 0, stream>>>(rp, ci, cv, dinv, xsA, DD, 0, xsB, DD);   // xs1
    k_hid<<<gN, 256, 0, stream>>>(xsB, W1, b1, gamma, beta, bn_mean, bn_var, hid3, 144, 0, 1);
    k_spmm<DD><<<gW, 256, 0, stream>>>(rp, ci, cv, dinv, xsB, DD, 0, xsA, DD);   // xs2
    k_hid<<<gN, 256, 0, stream>>>(xsA, W1, b1, gamma, beta, bn_mean, bn_var, hid3, 144, 48, 2);
    k_spmm<DD><<<gW, 256, 0, stream>>>(rp, ci, cv, dinv, xsA, DD, 0, xsB, DD);   // xs3
    k_hid<<<gN, 256, 0, stream>>>(xsB, W1, b1, gamma, beta, bn_mean, bn_var, hid3, 144, 96, 3);

    // batched hidden SpMM chains (xs arena dead from here)
    k_spmm<144><<<gW, 256, 0, stream>>>(rp, ci, cv, dinv, hid3, 144, 0, S1, 144);
    k_cellout<<<dim3(gN, 3), 256, 0, stream>>>(S1, 144, 0, W2, b2v, outcell, 1);
    k_spmm<96><<<gW, 256, 0, stream>>>(rp, ci, cv, dinv, S1, 144, 48, S2, 96);   // hid3 dead
    k_cellout<<<dim3(gN, 3), 256, 0, stream>>>(S2, 96, 0, W2, b2v, outcell, 2);
    k_spmm<48><<<gW, 256, 0, stream>>>(rp, ci, cv, dinv, S2, 96, 48, S3, 48);    // S1 dead
    k_cellout<<<dim3(gN, 3), 256, 0, stream>>>(S3, 48, 0, W2, b2v, outcell, 3);

    k_final<<<gN, 256, 0, stream>>>(outcell, Wout, bout, out);
}